// Round 4
// baseline (352.642 us; speedup 1.0000x reference)
//
#include <hip/hip_runtime.h>

// One thread processes a GROUP of 4 points (28 floats = 7 float4 per array).
// No LDS, no barriers: 21 independent 16B loads per thread give deep MLP;
// outputs are 40 floats = 10 aligned 16B nontemporal stores per thread.

typedef float floatx4 __attribute__((ext_vector_type(4)));

__device__ __forceinline__ void g2_point(const float* __restrict__ X,
                                         const float* __restrict__ Y,
                                         const float* __restrict__ Z,
                                         float* __restrict__ o) {
    float sxx = 0.f, sxy = 0.f, syy = 0.f, sxz = 0.f, syz = 0.f, szz = 0.f;
#pragma unroll
    for (int c = 0; c < 7; ++c) {
        sxx = fmaf(X[c], X[c], sxx);
        sxy = fmaf(X[c], Y[c], sxy);
        syy = fmaf(Y[c], Y[c], syy);
        sxz = fmaf(X[c], Z[c], sxz);
        syz = fmaf(Y[c], Z[c], syz);
        szz = fmaf(Z[c], Z[c], szz);
    }
#define W(a, b) (X[a] * Y[b] - X[b] * Y[a])
    // G2 cross product (Bryant convention), c_k = phi_ijk x_i y_j
    const float c0 = W(1, 2) + W(3, 4) + W(5, 6);
    const float c1 = W(2, 0) + W(3, 5) - W(4, 6);
    const float c2 = W(0, 1) - W(3, 6) - W(4, 5);
    const float c3 = W(4, 0) + W(5, 1) - W(6, 2);
    const float c4 = W(0, 3) + W(1, 6) + W(2, 5);
    const float c5 = W(6, 0) + W(1, 3) - W(2, 4);
    const float c6 = W(0, 5) - W(1, 4) - W(2, 3);
#undef W
    const float scc = c0 * c0 + c1 * c1 + c2 * c2 + c3 * c3 +
                      c4 * c4 + c5 * c5 + c6 * c6;
    const float tr = c0 * Z[0] + c1 * Z[1] + c2 * Z[2] + c3 * Z[3] +
                     c4 * Z[4] + c5 * Z[5] + c6 * Z[6];
    o[0] = sqrtf(sxx);   // ||x||
    o[1] = sxy;          // <x,y>
    o[2] = sqrtf(syy);   // ||y||
    o[3] = sqrtf(scc);   // ||x cross y||
    o[4] = sxz;          // <x,z>
    o[5] = syz;          // <y,z>
    o[6] = sqrtf(szz);   // ||z||
    o[7] = tr;           // phi(x,y,z) = <x cross y, z>
    o[8] = 0.f;          // phi(x,x,y) == 0 by antisymmetry
    o[9] = 0.f;          // phi(y,y,z) == 0 by antisymmetry
}

__global__ __launch_bounds__(256, 2) void g2_reg_kernel(
        const float* __restrict__ x,
        const float* __restrict__ y,
        const float* __restrict__ z,
        float* __restrict__ out,
        int npts) {
    const int g = blockIdx.x * 256 + threadIdx.x;  // group of 4 points
    const long long pbase = (long long)g * 4;
    if (pbase >= npts) return;

    if (pbase + 4 <= npts) {
        // ---- fast path: whole group in registers ----
        float ax[28], ay[28], az[28], o[40];
        const floatx4* x4 = (const floatx4*)x + (size_t)g * 7;
        const floatx4* y4 = (const floatx4*)y + (size_t)g * 7;
        const floatx4* z4 = (const floatx4*)z + (size_t)g * 7;
#pragma unroll
        for (int i = 0; i < 7; ++i) {
            *(floatx4*)&ax[4 * i] = x4[i];
            *(floatx4*)&ay[4 * i] = y4[i];
            *(floatx4*)&az[4 * i] = z4[i];
        }
#pragma unroll
        for (int p = 0; p < 4; ++p) {
            g2_point(&ax[7 * p], &ay[7 * p], &az[7 * p], &o[10 * p]);
        }
        floatx4* o4 = (floatx4*)out + (size_t)g * 10;
#pragma unroll
        for (int i = 0; i < 10; ++i) {
            __builtin_nontemporal_store(*(floatx4*)&o[4 * i], o4 + i);
        }
    } else {
        // ---- tail: scalar per point (never taken when npts % 4 == 0) ----
        for (long long p = pbase; p < npts; ++p) {
            float X[7], Y[7], Z[7], o[10];
#pragma unroll
            for (int c = 0; c < 7; ++c) {
                X[c] = x[p * 7 + c];
                Y[c] = y[p * 7 + c];
                Z[c] = z[p * 7 + c];
            }
            g2_point(X, Y, Z, o);
#pragma unroll
            for (int k = 0; k < 10; ++k) out[p * 10 + k] = o[k];
        }
    }
}

extern "C" void kernel_launch(void* const* d_in, const int* in_sizes, int n_in,
                              void* d_out, int out_size, void* d_ws, size_t ws_size,
                              hipStream_t stream) {
    const float* x = (const float*)d_in[0];
    const float* y = (const float*)d_in[1];
    const float* z = (const float*)d_in[2];
    float* out = (float*)d_out;
    const int npts = in_sizes[0] / 7;  // 256*16384 = 4194304
    const int ngroups = (npts + 3) / 4;
    const int nblocks = (ngroups + 255) / 256;
    g2_reg_kernel<<<nblocks, 256, 0, stream>>>(x, y, z, out, npts);
}

// Round 5
// 103.585 us; speedup vs baseline: 3.4044x; 3.4044x over previous
//
#include <hip/hip_runtime.h>

#define NPB 256  // points per chunk (= threads per block)
#define CPB 8    // chunks per block (persistent-ish pipelined loop)

typedef float floatx4 __attribute__((ext_vector_type(4)));

__device__ __forceinline__ void g2_point(const float* __restrict__ X,
                                         const float* __restrict__ Y,
                                         const float* __restrict__ Z,
                                         float* __restrict__ o) {
    float sxx = 0.f, sxy = 0.f, syy = 0.f, sxz = 0.f, syz = 0.f, szz = 0.f;
#pragma unroll
    for (int c = 0; c < 7; ++c) {
        sxx = fmaf(X[c], X[c], sxx);
        sxy = fmaf(X[c], Y[c], sxy);
        syy = fmaf(Y[c], Y[c], syy);
        sxz = fmaf(X[c], Z[c], sxz);
        syz = fmaf(Y[c], Z[c], syz);
        szz = fmaf(Z[c], Z[c], szz);
    }
#define W(a, b) (X[a] * Y[b] - X[b] * Y[a])
    // G2 cross product (Bryant convention), c_k = phi_ijk x_i y_j
    const float c0 = W(1, 2) + W(3, 4) + W(5, 6);
    const float c1 = W(2, 0) + W(3, 5) - W(4, 6);
    const float c2 = W(0, 1) - W(3, 6) - W(4, 5);
    const float c3 = W(4, 0) + W(5, 1) - W(6, 2);
    const float c4 = W(0, 3) + W(1, 6) + W(2, 5);
    const float c5 = W(6, 0) + W(1, 3) - W(2, 4);
    const float c6 = W(0, 5) - W(1, 4) - W(2, 3);
#undef W
    const float scc = c0 * c0 + c1 * c1 + c2 * c2 + c3 * c3 +
                      c4 * c4 + c5 * c5 + c6 * c6;
    const float tr = c0 * Z[0] + c1 * Z[1] + c2 * Z[2] + c3 * Z[3] +
                     c4 * Z[4] + c5 * Z[5] + c6 * Z[6];
    o[0] = sqrtf(sxx);   // ||x||
    o[1] = sxy;          // <x,y>
    o[2] = sqrtf(syy);   // ||y||
    o[3] = sqrtf(scc);   // ||x cross y||
    o[4] = sxz;          // <x,z>
    o[5] = syz;          // <y,z>
    o[6] = sqrtf(szz);   // ||z||
    o[7] = tr;           // phi(x,y,z) = <x cross y, z>
    o[8] = 0.f;          // phi(x,x,y) == 0 by antisymmetry
    o[9] = 0.f;          // phi(y,y,z) == 0 by antisymmetry
}

__global__ __launch_bounds__(256) void g2_pipe_kernel(
        const float* __restrict__ x,
        const float* __restrict__ y,
        const float* __restrict__ z,
        float* __restrict__ out,
        long long nfull) {  // number of full 256-point chunks
    // Double-buffered input staging (2 x 21504 B) + output staging (10240 B)
    // = 53248 B -> 3 blocks/CU. Prefetch for chunk k+1 is issued into
    // registers before the compute phase of chunk k; the __syncthreads()
    // vmcnt drain thus lands AFTER ~a full compute phase of overlap (T14).
    __shared__ float buf[2][NPB * 7 * 3];
    __shared__ float so[NPB * 10];

    const int t = threadIdx.x;
    const long long c0 = (long long)blockIdx.x * CPB;
    const int myc = (int)min((long long)CPB, nfull - c0);
    if (myc <= 0) return;

    floatx4 rx0, ry0, rz0, rx1, ry1, rz1;

    // issue global loads for chunk c into registers (no wait here)
    auto issue = [&](long long c) {
        const floatx4* gx = (const floatx4*)x + c * 448;  // 448 float4 = 1792 f
        const floatx4* gy = (const floatx4*)y + c * 448;
        const floatx4* gz = (const floatx4*)z + c * 448;
        rx0 = gx[t]; ry0 = gy[t]; rz0 = gz[t];
        if (t < 192) {  // wave-uniform: waves 0-2 take it, wave 3 skips
            rx1 = gx[t + 256]; ry1 = gy[t + 256]; rz1 = gz[t + 256];
        }
    };
    // commit register-staged chunk into LDS buffer b
    auto write_lds = [&](int b) {
        floatx4* lx = (floatx4*)&buf[b][0];
        floatx4* ly = (floatx4*)&buf[b][NPB * 7];
        floatx4* lz = (floatx4*)&buf[b][NPB * 7 * 2];
        lx[t] = rx0; ly[t] = ry0; lz[t] = rz0;
        if (t < 192) {
            lx[t + 256] = rx1; ly[t + 256] = ry1; lz[t + 256] = rz1;
        }
    };

    // prologue: stage first chunk
    issue(c0);
    write_lds(0);
    __syncthreads();

    int cur = 0;
    for (int k = 0; k < myc; ++k) {
        const long long c = c0 + k;
        const bool pref = (k + 1 < myc);
        if (pref) issue(c + 1);  // async: waited at B1, after compute overlap

        // ---- compute chunk c from buf[cur] ----
        const float* sx = &buf[cur][0];
        const float* sy = &buf[cur][NPB * 7];
        const float* sz = &buf[cur][NPB * 7 * 2];
        float X[7], Y[7], Z[7], o[10];
#pragma unroll
        for (int q = 0; q < 7; ++q) {
            X[q] = sx[t * 7 + q];
            Y[q] = sy[t * 7 + q];
            Z[q] = sz[t * 7 + q];
        }
        g2_point(X, Y, Z, o);
#pragma unroll
        for (int q = 0; q < 10; ++q) so[t * 10 + q] = o[q];
        __syncthreads();  // B1: so published; prefetch loads drained here

        // ---- coalesced nontemporal output stores (full lines per instr) ----
        {
            floatx4* go = (floatx4*)out + c * 640;  // 640 float4 = 2560 f
            const floatx4* lo = (const floatx4*)so;
            __builtin_nontemporal_store(lo[t], go + t);
            __builtin_nontemporal_store(lo[t + 256], go + t + 256);
            if (t < 128)  // wave-uniform: waves 0-1
                __builtin_nontemporal_store(lo[t + 512], go + t + 512);
        }
        if (pref) write_lds(cur ^ 1);
        __syncthreads();  // B2: next buffer published; so safe to overwrite
        cur ^= 1;
    }
}

// tail: handles npts % 256 leftover points (not taken for this problem size)
__global__ void g2_tail_kernel(const float* __restrict__ x,
                               const float* __restrict__ y,
                               const float* __restrict__ z,
                               float* __restrict__ out,
                               long long start, long long npts) {
    long long p = start + threadIdx.x;
    if (p >= npts) return;
    float X[7], Y[7], Z[7], o[10];
#pragma unroll
    for (int c = 0; c < 7; ++c) {
        X[c] = x[p * 7 + c];
        Y[c] = y[p * 7 + c];
        Z[c] = z[p * 7 + c];
    }
    g2_point(X, Y, Z, o);
#pragma unroll
    for (int k = 0; k < 10; ++k) out[p * 10 + k] = o[k];
}

extern "C" void kernel_launch(void* const* d_in, const int* in_sizes, int n_in,
                              void* d_out, int out_size, void* d_ws, size_t ws_size,
                              hipStream_t stream) {
    const float* x = (const float*)d_in[0];
    const float* y = (const float*)d_in[1];
    const float* z = (const float*)d_in[2];
    float* out = (float*)d_out;
    const long long npts = (long long)in_sizes[0] / 7;  // 4194304
    const long long nfull = npts / NPB;                 // 16384 full chunks
    if (nfull > 0) {
        const int nblocks = (int)((nfull + CPB - 1) / CPB);  // 2048
        g2_pipe_kernel<<<nblocks, 256, 0, stream>>>(x, y, z, out, nfull);
    }
    if (npts % NPB) {
        g2_tail_kernel<<<1, 256, 0, stream>>>(x, y, z, out, nfull * NPB, npts);
    }
}